// Round 7
// baseline (1687.971 us; speedup 1.0000x reference)
//
#include <hip/hip_runtime.h>
#include <hip/hip_bf16.h>
#include <stdint.h>

// HMPNN layer: two NNConv(sum-agg)+sigmoid, concat, Linear(32,32), sigmoid.
// R4: fused edge dispatch, global atomics: edge 133us.
// R5-R8: fine buckets; learned scattered-8B-store wall + latency walls.
// R9/R10: coarse 512-node bins, LDS-staged scatter (runs contiguous, ~35us),
//     streaming edge kernel. Edge stuck at 205-208us: col->gather dependent
//     chain exposes ~400cy mid-iteration (gathers issue with <1 compute of
//     lead); only ~3 lines/wave in flight -> 760GB/s (Little's law).
//     ALSO: totals across ALL rounds fit "30us per dispatch" fixed overhead
//     (5 dispatches = ~150us of the 414).
// R11: (1) 5 -> 3 dispatches: prep_w folded into scatter grid; ovf_cleanup
//         folded into finalize behind __syncthreads_or fast path (per-block
//         ovf lists, no global ovf counter -> nothing needs pre-zeroing).
//      (2) edge_mfma 3-stage pipeline: col[i+2] issue / gather[i+1] issue /
//         compute[i]. col is resident when gathers issue (no mid-iter wait);
//         gathers get ~1 full iteration of lead. __launch_bounds__(512,4).
//      Predict: edge 208->~70us, total ~210us.

#define NN 50000
#define EE 800000
#define SHIFT 9                 // 512 nodes per bin
#define CBIN 512
#define BPM 98                  // bins per metastep
#define ABLK 8192               // edges per scatter block
#define ABM 98                  // ceil(800000/8192)
#define CAPB_MAX 112            // per-(bin,ablock) cap: mean 84, sigma 9.1
#define SUBS 4                  // aggregation sub-blocks per bin
#define OVB ABLK                // per-scatter-block ovf capacity (absolute bound)

typedef __attribute__((ext_vector_type(8))) short short8;
typedef __attribute__((ext_vector_type(4))) float f32x4;

union U8 { short8 v; unsigned int u[4]; };

__device__ __forceinline__ unsigned short f2bf_rne(float f) {
    union { float fl; unsigned int i; } v; v.fl = f;
    unsigned int x = v.i;
    x += 0x7FFFu + ((x >> 16) & 1u);
    return (unsigned short)(x >> 16);
}

__device__ __forceinline__ unsigned int pack2bf(float a, float b) {
    __hip_bfloat162 h = __float22bfloat162_rn(float2{a, b}); // x=low, y=high
    union { __hip_bfloat162 h2; unsigned int u; } c; c.h2 = h;
    return c.u;
}

// Dispatch 1: blocks 0..2*ABM-1 scatter edges; blocks 2*ABM, 2*ABM+1 build wf.
// Scatter: LDS histogram -> prefix -> bin-sorted staging -> coalesced copy-out
// (consecutive threads write consecutive col slots). Overflow (p>=capb) goes
// to THIS block's private ovf list; ovf_n[bid] written unconditionally each
// run (no stale state, no pre-zeroing dispatch needed).
__global__ __launch_bounds__(1024) void scatter_prep(
    const int* __restrict__ ei_a, const int* __restrict__ ei_b,
    const float* __restrict__ w_msg_a, const float* __restrict__ b_msg_a,
    unsigned short* __restrict__ wf_a,
    const float* __restrict__ w_msg_b, const float* __restrict__ b_msg_b,
    unsigned short* __restrict__ wf_b,
    unsigned int* __restrict__ cntA, uint2* __restrict__ col, int capb,
    unsigned int* __restrict__ ovf_n, unsigned int* __restrict__ ovf)
{
    int bid = blockIdx.x;
    int tid = threadIdx.x;
    if (bid >= 2 * ABM) {                       // prep blocks
        const float* w_msg = (bid & 1) ? w_msg_b : w_msg_a;
        const float* b_msg = (bid & 1) ? b_msg_b : b_msg_a;
        unsigned short* wfrag = (bid & 1) ? wf_b : wf_a;
        for (int idx = tid; idx < 9 * 64 * 8; idx += 1024) {
            int j = idx & 7;
            int lane = (idx >> 3) & 63;
            int t = idx >> 9;
            int n = lane & 15;
            int qb = (lane >> 4) & 1;
            int q2 = (lane >> 5) & 1;
            int i = qb * 8 + j;
            int f = (t < 8) ? (8 * q2 + t) : (16 + q2);
            float v = (f < 16) ? w_msg[f * 256 + i * 16 + n]
                               : (f == 16 ? b_msg[i * 16 + n] : 0.f);
            wfrag[idx] = f2bf_rne(v);
        }
        return;
    }

    int ms = bid >= ABM;
    int ablk = ms ? bid - ABM : bid;
    const int* __restrict__ ei = ms ? ei_b : ei_a;

    __shared__ uint2 stage[ABLK];               // 64 KB
    __shared__ unsigned int lcnt[BPM];
    __shared__ unsigned int loff[BPM + 1];
    __shared__ unsigned int lovf;

    if (tid < BPM) lcnt[tid] = 0u;
    if (tid == 0) lovf = 0u;
    __syncthreads();

    int e0 = ablk * ABLK;
    int srcv[8], dstv[8];
    unsigned int rr[8];
    #pragma unroll
    for (int k = 0; k < 8; ++k) {
        int e = e0 + k * 1024 + tid;
        bool v = e < EE;
        int dst = v ? ei[EE + e] : 0;
        int src = v ? ei[e] : 0;
        srcv[k] = src; dstv[k] = dst;
        rr[k] = v ? atomicAdd(&lcnt[dst >> SHIFT], 1u) : 0u;
    }
    __syncthreads();

    if (tid <= BPM) {                           // O(n^2) exclusive prefix, 98 bins
        unsigned int s = 0;
        for (int b = 0; b < tid; ++b) s += lcnt[b];
        loff[tid] = s;
    }
    if (tid < BPM)
        cntA[(size_t)(ms * BPM + tid) * ABM + ablk] = lcnt[tid];
    __syncthreads();

    #pragma unroll
    for (int k = 0; k < 8; ++k) {
        int e = e0 + k * 1024 + tid;
        if (e >= EE) continue;
        int dst = dstv[k];
        int bin = dst >> SHIFT;
        stage[loff[bin] + rr[k]] =
            uint2{(unsigned int)srcv[k],
                  (unsigned int)(e | ((dst & (CBIN - 1)) << 20))};
    }
    __syncthreads();

    int tot = (int)loff[BPM];
    for (int i = tid; i < tot; i += 1024) {
        int lo = 0, hi = BPM;
        while (hi - lo > 1) {
            int mid = (lo + hi) >> 1;
            if ((int)loff[mid] <= i) lo = mid; else hi = mid;
        }
        int p = i - (int)loff[lo];
        if (p < capb) {
            col[((size_t)(ms * BPM + lo) * ABM + ablk) * capb + p] = stage[i];
        } else {
            unsigned int r = atomicAdd(&lovf, 1u);
            if (r < OVB) ovf[(size_t)bid * OVB + r] = stage[i].y & 0xFFFFFu;
        }
    }
    __syncthreads();
    if (tid == 0) ovf_n[bid] = (lovf < OVB) ? lovf : OVB;
}

#define ADV(T) { T##_ch++; \
    while (T##_g < ABM && T##_ch * 16 >= T##_len) { \
        T##_g += 32; T##_ch = 0; T##_len = (T##_g < ABM) ? s_len[T##_g] : 0; } }

#define LOADPE(T, PE, VM) { int _s = T##_ch * 16 + m; \
    VM = (T##_g < ABM) && (_s < T##_len); \
    PE = VM ? colb[(size_t)T##_g * capb + _s] : uint2{0u, 0u}; }

#define GATHER(PE, X0, X1, A0, A1) { \
    const float4* _xr = (const float4*)(x + (size_t)(PE).x * 16); \
    X0 = _xr[qb * 2]; X1 = _xr[qb * 2 + 1]; \
    const float4* _ar = (const float4*)(attr + (size_t)((PE).y & 0xFFFFFu) * 16); \
    A0 = _ar[q2 * 2]; A1 = _ar[q2 * 2 + 1]; }

// One block per (bin, ms, sub). 3-stage pipeline per wave:
//   stage A: col entry load issued (2 iterations ahead; resident when used)
//   stage B: x/attr gathers issued (1 iteration + compute of lead)
//   stage C: MFMA compute + LDS-atomic into the 512x16 tile
// No mid-iteration col wait -> gathers fill the memory pipe.
__global__ __launch_bounds__(512, 4) void edge_mfma(
    const float* __restrict__ ea_a, const float* __restrict__ x_a,
    const unsigned short* __restrict__ wf_a,
    const float* __restrict__ ea_b, const float* __restrict__ x_b,
    const unsigned short* __restrict__ wf_b,
    const unsigned int* __restrict__ cntA, const uint2* __restrict__ col,
    int capb, float* __restrict__ partial)
{
    int bid = blockIdx.x;
    int bin = bid >> 3;
    int ms  = (bid >> 2) & 1;
    int sub = bid & 3;
    const float* __restrict__ attr = ms ? ea_b : ea_a;
    const float* __restrict__ x    = ms ? x_b : x_a;
    const unsigned short* __restrict__ wfrag = ms ? wf_b : wf_a;

    __shared__ float tile[CBIN * 16];           // 32 KB
    __shared__ int s_len[ABM];

    int tid = threadIdx.x;
    for (int i = tid; i < CBIN * 16; i += 512) tile[i] = 0.f;
    size_t cbase = (size_t)(ms * BPM + bin) * ABM;
    if (tid < ABM) {
        int v = (int)cntA[cbase + tid];
        s_len[tid] = v < capb ? v : capb;
    }
    __syncthreads();

    int lane = tid & 63, wid = tid >> 6;
    int m = lane & 15, quad = lane >> 4;
    int q2 = quad >> 1, qb = quad & 1;

    short8 bfr[9];
    #pragma unroll
    for (int t = 0; t < 9; ++t)
        bfr[t] = ((const short8*)wfrag)[t * 64 + lane];

    const uint2* __restrict__ colb = col + cbase * capb;
    int sl = sub * 8 + wid;                     // slice 0..31, ablks sl, sl+32, ...

    int tC_g = sl, tC_ch = -1, tC_len = (sl < ABM) ? s_len[sl] : 0;
    ADV(tC);
    int tB_g = tC_g, tB_ch = tC_ch, tB_len = tC_len;
    ADV(tB);
    int tA_g = tB_g, tA_ch = tB_ch, tA_len = tB_len;
    ADV(tA);

    uint2 peC, peB, peA;
    bool vmC, vmB, vmA;
    float4 xC0, xC1, aC0, aC1, xB0, xB1, aB0, aB1;
    LOADPE(tC, peC, vmC);
    LOADPE(tB, peB, vmB);
    GATHER(peC, xC0, xC1, aC0, aC1);

    while (tC_g < ABM) {
        LOADPE(tA, peA, vmA);                   // col 2 ahead (no use this iter)
        GATHER(peB, xB0, xB1, aB0, aB1);        // gathers 1 ahead (peB resident)

        // ---- compute stage C ----
        float zf = vmC ? 1.f : 0.f;
        float xh[8] = {xC0.x * zf, xC0.y * zf, xC0.z * zf, xC0.w * zf,
                       xC1.x * zf, xC1.y * zf, xC1.z * zf, xC1.w * zf};
        float ah[8] = {aC0.x, aC0.y, aC0.z, aC0.w, aC1.x, aC1.y, aC1.z, aC1.w};

        f32x4 acc = {0.f, 0.f, 0.f, 0.f};
        #pragma unroll
        for (int t = 0; t < 8; ++t) {
            U8 a;
            #pragma unroll
            for (int jj = 0; jj < 4; ++jj)
                a.u[jj] = pack2bf(ah[t] * xh[2 * jj], ah[t] * xh[2 * jj + 1]);
            acc = __builtin_amdgcn_mfma_f32_16x16x32_bf16(a.v, bfr[t], acc, 0, 0, 0);
        }
        U8 a8;
        #pragma unroll
        for (int jj = 0; jj < 4; ++jj)
            a8.u[jj] = (q2 == 0) ? pack2bf(xh[2 * jj], xh[2 * jj + 1]) : 0u;
        acc = __builtin_amdgcn_mfma_f32_16x16x32_bf16(a8.v, bfr[8], acc, 0, 0, 0);

        int dl = (int)((peC.y >> 20) & (CBIN - 1));
        #pragma unroll
        for (int r = 0; r < 4; ++r) {
            int s2 = tC_ch * 16 + quad * 4 + r;
            int dlr = __shfl(dl, quad * 4 + r);
            if (s2 < tC_len)
                atomicAdd(&tile[dlr * 16 + m], acc[r]);
        }

        // ---- rotate ----
        tC_g = tB_g; tC_ch = tB_ch; tC_len = tB_len; peC = peB; vmC = vmB;
        xC0 = xB0; xC1 = xB1; aC0 = aB0; aC1 = aB1;
        tB_g = tA_g; tB_ch = tA_ch; tB_len = tA_len; peB = peA; vmB = vmA;
        ADV(tA);
    }
    __syncthreads();

    float* __restrict__ pt =
        partial + ((size_t)(ms * BPM + bin) * SUBS + sub) * (CBIN * 16);
    for (int i = tid; i < CBIN * 16; i += 512) pt[i] = tile[i];
}

// out[n,d] = sigmoid( h @ w_lin + b_lin ), h = sigmoid(sum partial + x@root
// + bias [+ exact-f32 overflow contributions, expected none]).
__global__ __launch_bounds__(256) void finalize(
    const float* __restrict__ xind, const float* __restrict__ partial,
    const int* __restrict__ ei_a, const float* __restrict__ ea_a,
    const float* __restrict__ x_a,
    const float* __restrict__ w_msg_a, const float* __restrict__ b_msg_a,
    const int* __restrict__ ei_b, const float* __restrict__ ea_b,
    const float* __restrict__ x_b,
    const float* __restrict__ w_msg_b, const float* __restrict__ b_msg_b,
    const unsigned int* __restrict__ ovf_n, const unsigned int* __restrict__ ovf,
    const float* __restrict__ root_a, const float* __restrict__ bias_a,
    const float* __restrict__ root_b, const float* __restrict__ bias_b,
    const float* __restrict__ w_lin, const float* __restrict__ b_lin,
    float* __restrict__ out)
{
    int tid = threadIdx.x;
    int n = blockIdx.x * 8 + (tid >> 5);        // grid exact: n < NN always
    int d = tid & 31;
    int lane = tid & 63;
    int gb32 = lane & ~31;

    int nzv = 0;
    if (tid < 2 * ABM) nzv = (int)ovf_n[tid];
    int any_ovf = __syncthreads_or(nzv);

    float xv = xind[n * 16 + (d & 15)];

    int j = d & 15;
    int ms = (d < 16) ? 0 : 1;
    const float* root = ms ? root_b : root_a;
    const float* bias = ms ? bias_b : bias_a;

    int bin = n >> SHIFT, dl = n & (CBIN - 1);
    const float* pa = partial + ((size_t)(ms * BPM + bin) * SUBS) * (CBIN * 16)
                      + (size_t)dl * 16 + j;
    float acc = pa[0] + pa[CBIN * 16] + pa[2 * CBIN * 16] + pa[3 * CBIN * 16]
                + bias[j];
    #pragma unroll
    for (int i = 0; i < 16; ++i) {
        float xiv = __shfl(xv, gb32 + i);
        acc += xiv * root[i * 16 + j];
    }

    if (any_ovf) {                               // rare exact-f32 fallback
        for (int b2 = 0; b2 < 2 * ABM; ++b2) {
            unsigned int c2 = ovf_n[b2];
            if (!c2) continue;
            int ms2 = b2 >= ABM;
            if (ms2 != ms) continue;
            const int* ei = ms2 ? ei_b : ei_a;
            const float* ea = ms2 ? ea_b : ea_a;
            const float* xs = ms2 ? x_b : x_a;
            const float* w_msg = ms2 ? w_msg_b : w_msg_a;
            const float* b_msg = ms2 ? b_msg_b : b_msg_a;
            for (unsigned int q = 0; q < c2; ++q) {
                int e = (int)ovf[(size_t)b2 * OVB + q];
                int dst = ei[EE + e];
                if (dst != n) continue;
                int src = ei[e];
                const float* ar = ea + (size_t)e * 16;
                const float* xj = xs + (size_t)src * 16;
                float ae = 0.f;
                #pragma unroll
                for (int i = 0; i < 16; ++i) {
                    float we = b_msg[i * 16 + j];
                    #pragma unroll
                    for (int f = 0; f < 16; ++f)
                        we += ar[f] * w_msg[f * 256 + i * 16 + j];
                    ae += xj[i] * we;
                }
                acc += ae;
            }
        }
    }

    float h = 1.f / (1.f + __expf(-acc));

    float acc2 = b_lin[d];
    #pragma unroll
    for (int jj = 0; jj < 32; ++jj) {
        float hj = __shfl(h, gb32 + jj);
        acc2 += hj * w_lin[jj * 32 + d];
    }
    out[(size_t)n * 32 + d] = 1.f / (1.f + __expf(-acc2));
}

extern "C" void kernel_launch(void* const* d_in, const int* in_sizes, int n_in,
                              void* d_out, int out_size, void* d_ws, size_t ws_size,
                              hipStream_t stream) {
    (void)in_sizes; (void)n_in; (void)out_size;
    const float* x_indivi = (const float*)d_in[0];
    const float* x_src_a  = (const float*)d_in[1];
    const float* x_src_b  = (const float*)d_in[2];
    const int*   ei_a     = (const int*)d_in[3];
    const int*   ei_b     = (const int*)d_in[4];
    const float* ea_a     = (const float*)d_in[5];
    const float* ea_b     = (const float*)d_in[6];
    const float* w_msg_a  = (const float*)d_in[7];
    const float* b_msg_a  = (const float*)d_in[8];
    const float* root_a   = (const float*)d_in[9];
    const float* bias_a   = (const float*)d_in[10];
    const float* w_msg_b  = (const float*)d_in[11];
    const float* b_msg_b  = (const float*)d_in[12];
    const float* root_b   = (const float*)d_in[13];
    const float* bias_b   = (const float*)d_in[14];
    const float* w_lin    = (const float*)d_in[15];
    const float* b_lin    = (const float*)d_in[16];
    float* out = (float*)d_out;

    char* ws = (char*)d_ws;
    size_t off = 0;
    auto alloc = [&](size_t bytes) -> void* {
        void* p = ws + off;
        off += (bytes + 255) & ~(size_t)255;
        return p;
    };
    unsigned short* wf_a = (unsigned short*)alloc(9 * 64 * 8 * 2);       // 9216 B
    unsigned short* wf_b = (unsigned short*)alloc(9 * 64 * 8 * 2);
    unsigned int* cntA   = (unsigned int*)alloc((size_t)2 * BPM * ABM * 4); // 77 KB
    unsigned int* ovf_n  = (unsigned int*)alloc((size_t)2 * ABM * 4);
    unsigned int* ovf    = (unsigned int*)alloc((size_t)2 * ABM * OVB * 4); // 6.4 MB
    float* partial = (float*)alloc((size_t)2 * BPM * SUBS * CBIN * 16 * 4); // 25.7 MB
    // col from remaining workspace; capb <= 112 (mean 84, sigma 9.1). Shrink
    // is safe: overflow edges go through the finalize fallback (exact f32).
    size_t avail = ws_size > off ? ws_size - off : 0;
    int capb = (int)(avail / ((size_t)2 * BPM * ABM * 8));
    if (capb > CAPB_MAX) capb = CAPB_MAX;
    uint2* col = (uint2*)(ws + off);

    scatter_prep<<<2 * ABM + 2, 1024, 0, stream>>>(
        ei_a, ei_b, w_msg_a, b_msg_a, wf_a, w_msg_b, b_msg_b, wf_b,
        cntA, col, capb, ovf_n, ovf);

    edge_mfma<<<BPM * 2 * SUBS, 512, 0, stream>>>(
        ea_a, x_src_a, wf_a, ea_b, x_src_b, wf_b, cntA, col, capb, partial);

    finalize<<<(NN + 7) / 8, 256, 0, stream>>>(
        x_indivi, partial,
        ei_a, ea_a, x_src_a, w_msg_a, b_msg_a,
        ei_b, ea_b, x_src_b, w_msg_b, b_msg_b,
        ovf_n, ovf,
        root_a, bias_a, root_b, bias_b, w_lin, b_lin, out);
}

// Round 8
// 359.670 us; speedup vs baseline: 4.6931x; 4.6931x over previous
//
#include <hip/hip_runtime.h>
#include <hip/hip_bf16.h>
#include <stdint.h>

// HMPNN layer: two NNConv(sum-agg)+sigmoid, concat, Linear(32,32), sigmoid.
// R4: fused edge dispatch, global atomics: edge 133us.
// R5-R8: fine buckets; scattered-8B-store wall + latency walls.
// R9/R10: coarse 512-node bins, LDS-staged scatter (~35us), streaming edge
//     kernel; edge 205-208us at BOTH occ 15% and 30% -> not wave-starved;
//     760GB/s cap is per-wave in-flight depth / random-64B efficiency.
// R11: fused dispatches + 3-stage pipeline, BUT runtime capb sizing hit the
//     real ws (~37-45MB) -> capb << 84 -> mass overflow -> serial fallback in
//     finalize = 1395us. Lesson: ws_size is ~37MB+ (R9's fixed 37MB layout
//     worked); "expected-zero" overflow was actually huge in R10/R11.
// R12: revert finalize to lean form; parallel ovf_cleanup kernel returns;
//     COMPILE-TIME budget 33.4MB (< proven 37MB): capb=112 fixed, SUBS=2
//     (occupancy proven irrelevant to edge), OVB=4096. Keep R11's 3-stage
//     edge pipeline -- this round finally measures it.
//     Predict: finalize ~15us, edge 70-120us if pipeline works (else 208),
//     total ~280-400us.

#define NN 50000
#define EE 800000
#define SHIFT 9                 // 512 nodes per bin
#define CBIN 512
#define BPM 98                  // bins per metastep
#define ABLK 8192               // edges per scatter block
#define ABM 98                  // ceil(800000/8192)
#define CAPB 112                // fixed: mean 84, sigma 9.1 -> +3 sigma
#define SUBS 2                  // aggregation sub-blocks per bin
#define SLICES 16               // SUBS * 8 waves
#define OVB 4096                // per-scatter-block ovf capacity

typedef __attribute__((ext_vector_type(8))) short short8;
typedef __attribute__((ext_vector_type(4))) float f32x4;

union U8 { short8 v; unsigned int u[4]; };

__device__ __forceinline__ unsigned short f2bf_rne(float f) {
    union { float fl; unsigned int i; } v; v.fl = f;
    unsigned int x = v.i;
    x += 0x7FFFu + ((x >> 16) & 1u);
    return (unsigned short)(x >> 16);
}

__device__ __forceinline__ unsigned int pack2bf(float a, float b) {
    __hip_bfloat162 h = __float22bfloat162_rn(float2{a, b}); // x=low, y=high
    union { __hip_bfloat162 h2; unsigned int u; } c; c.h2 = h;
    return c.u;
}

// Dispatch 1: blocks 0..2*ABM-1 scatter; blocks 2*ABM,2*ABM+1 build wf.
// Scatter: LDS histogram -> prefix -> bin-sorted staging -> coalesced
// copy-out. Overflow (p>=CAPB, true tail only) -> this block's private list;
// ovf_n[bid] written unconditionally (no pre-zeroing dispatch needed).
__global__ __launch_bounds__(1024) void scatter_prep(
    const int* __restrict__ ei_a, const int* __restrict__ ei_b,
    const float* __restrict__ w_msg_a, const float* __restrict__ b_msg_a,
    unsigned short* __restrict__ wf_a,
    const float* __restrict__ w_msg_b, const float* __restrict__ b_msg_b,
    unsigned short* __restrict__ wf_b,
    unsigned int* __restrict__ cntA, uint2* __restrict__ col,
    unsigned int* __restrict__ ovf_n, unsigned int* __restrict__ ovf)
{
    int bid = blockIdx.x;
    int tid = threadIdx.x;
    if (bid >= 2 * ABM) {                       // prep blocks
        const float* w_msg = (bid & 1) ? w_msg_b : w_msg_a;
        const float* b_msg = (bid & 1) ? b_msg_b : b_msg_a;
        unsigned short* wfrag = (bid & 1) ? wf_b : wf_a;
        for (int idx = tid; idx < 9 * 64 * 8; idx += 1024) {
            int j = idx & 7;
            int lane = (idx >> 3) & 63;
            int t = idx >> 9;
            int n = lane & 15;
            int qb = (lane >> 4) & 1;
            int q2 = (lane >> 5) & 1;
            int i = qb * 8 + j;
            int f = (t < 8) ? (8 * q2 + t) : (16 + q2);
            float v = (f < 16) ? w_msg[f * 256 + i * 16 + n]
                               : (f == 16 ? b_msg[i * 16 + n] : 0.f);
            wfrag[idx] = f2bf_rne(v);
        }
        return;
    }

    int ms = bid >= ABM;
    int ablk = ms ? bid - ABM : bid;
    const int* __restrict__ ei = ms ? ei_b : ei_a;

    __shared__ uint2 stage[ABLK];               // 64 KB
    __shared__ unsigned int lcnt[BPM];
    __shared__ unsigned int loff[BPM + 1];
    __shared__ unsigned int lovf;

    if (tid < BPM) lcnt[tid] = 0u;
    if (tid == 0) lovf = 0u;
    __syncthreads();

    int e0 = ablk * ABLK;
    int srcv[8], dstv[8];
    unsigned int rr[8];
    #pragma unroll
    for (int k = 0; k < 8; ++k) {
        int e = e0 + k * 1024 + tid;
        bool v = e < EE;
        int dst = v ? ei[EE + e] : 0;
        int src = v ? ei[e] : 0;
        srcv[k] = src; dstv[k] = dst;
        rr[k] = v ? atomicAdd(&lcnt[dst >> SHIFT], 1u) : 0u;
    }
    __syncthreads();

    if (tid <= BPM) {                           // O(n^2) exclusive prefix
        unsigned int s = 0;
        for (int b = 0; b < tid; ++b) s += lcnt[b];
        loff[tid] = s;
    }
    if (tid < BPM)
        cntA[(size_t)(ms * BPM + tid) * ABM + ablk] = lcnt[tid];
    __syncthreads();

    #pragma unroll
    for (int k = 0; k < 8; ++k) {
        int e = e0 + k * 1024 + tid;
        if (e >= EE) continue;
        int dst = dstv[k];
        int bin = dst >> SHIFT;
        stage[loff[bin] + rr[k]] =
            uint2{(unsigned int)srcv[k],
                  (unsigned int)(e | ((dst & (CBIN - 1)) << 20))};
    }
    __syncthreads();

    int tot = (int)loff[BPM];
    for (int i = tid; i < tot; i += 1024) {
        int lo = 0, hi = BPM;
        while (hi - lo > 1) {
            int mid = (lo + hi) >> 1;
            if ((int)loff[mid] <= i) lo = mid; else hi = mid;
        }
        int p = i - (int)loff[lo];
        if (p < CAPB) {
            col[((size_t)(ms * BPM + lo) * ABM + ablk) * CAPB + p] = stage[i];
        } else {
            unsigned int r = atomicAdd(&lovf, 1u);
            if (r < OVB) ovf[(size_t)bid * OVB + r] = stage[i].y & 0xFFFFFu;
        }
    }
    __syncthreads();
    if (tid == 0) ovf_n[bid] = (lovf < OVB) ? lovf : OVB;
}

#define ADV(T) { T##_ch++; \
    while (T##_g < ABM && T##_ch * 16 >= T##_len) { \
        T##_g += SLICES; T##_ch = 0; T##_len = (T##_g < ABM) ? s_len[T##_g] : 0; } }

#define LOADPE(T, PE, VM) { int _s = T##_ch * 16 + m; \
    VM = (T##_g < ABM) && (_s < T##_len); \
    PE = VM ? colb[(size_t)T##_g * CAPB + _s] : uint2{0u, 0u}; }

#define GATHER(PE, X0, X1, A0, A1) { \
    const float4* _xr = (const float4*)(x + (size_t)(PE).x * 16); \
    X0 = _xr[qb * 2]; X1 = _xr[qb * 2 + 1]; \
    const float4* _ar = (const float4*)(attr + (size_t)((PE).y & 0xFFFFFu) * 16); \
    A0 = _ar[q2 * 2]; A1 = _ar[q2 * 2 + 1]; }

// One block per (bin, ms, sub). 3-stage pipeline per wave:
//   A: col entry load issued 2 iterations ahead (resident when gathered from)
//   B: x/attr gathers issued 1 iteration ahead
//   C: MFMA compute + LDS-atomic into the 512x16 tile
__global__ __launch_bounds__(512, 4) void edge_mfma(
    const float* __restrict__ ea_a, const float* __restrict__ x_a,
    const unsigned short* __restrict__ wf_a,
    const float* __restrict__ ea_b, const float* __restrict__ x_b,
    const unsigned short* __restrict__ wf_b,
    const unsigned int* __restrict__ cntA, const uint2* __restrict__ col,
    float* __restrict__ partial)
{
    int bid = blockIdx.x;
    int bin = bid >> 2;
    int ms  = (bid >> 1) & 1;
    int sub = bid & 1;
    const float* __restrict__ attr = ms ? ea_b : ea_a;
    const float* __restrict__ x    = ms ? x_b : x_a;
    const unsigned short* __restrict__ wfrag = ms ? wf_b : wf_a;

    __shared__ float tile[CBIN * 16];           // 32 KB
    __shared__ int s_len[ABM];

    int tid = threadIdx.x;
    for (int i = tid; i < CBIN * 16; i += 512) tile[i] = 0.f;
    size_t cbase = (size_t)(ms * BPM + bin) * ABM;
    if (tid < ABM) {
        int v = (int)cntA[cbase + tid];
        s_len[tid] = v < CAPB ? v : CAPB;
    }
    __syncthreads();

    int lane = tid & 63, wid = tid >> 6;
    int m = lane & 15, quad = lane >> 4;
    int q2 = quad >> 1, qb = quad & 1;

    short8 bfr[9];
    #pragma unroll
    for (int t = 0; t < 9; ++t)
        bfr[t] = ((const short8*)wfrag)[t * 64 + lane];

    const uint2* __restrict__ colb = col + cbase * CAPB;
    int sl = sub * 8 + wid;                     // slice 0..15, ablks sl, sl+16,...

    int tC_g = sl, tC_ch = -1, tC_len = (sl < ABM) ? s_len[sl] : 0;
    ADV(tC);
    int tB_g = tC_g, tB_ch = tC_ch, tB_len = tC_len;
    ADV(tB);
    int tA_g = tB_g, tA_ch = tB_ch, tA_len = tB_len;
    ADV(tA);

    uint2 peC, peB, peA;
    bool vmC, vmB, vmA;
    float4 xC0, xC1, aC0, aC1, xB0, xB1, aB0, aB1;
    LOADPE(tC, peC, vmC);
    LOADPE(tB, peB, vmB);
    GATHER(peC, xC0, xC1, aC0, aC1);

    while (tC_g < ABM) {
        LOADPE(tA, peA, vmA);                   // col 2 ahead
        GATHER(peB, xB0, xB1, aB0, aB1);        // gathers 1 ahead

        float zf = vmC ? 1.f : 0.f;
        float xh[8] = {xC0.x * zf, xC0.y * zf, xC0.z * zf, xC0.w * zf,
                       xC1.x * zf, xC1.y * zf, xC1.z * zf, xC1.w * zf};
        float ah[8] = {aC0.x, aC0.y, aC0.z, aC0.w, aC1.x, aC1.y, aC1.z, aC1.w};

        f32x4 acc = {0.f, 0.f, 0.f, 0.f};
        #pragma unroll
        for (int t = 0; t < 8; ++t) {
            U8 a;
            #pragma unroll
            for (int jj = 0; jj < 4; ++jj)
                a.u[jj] = pack2bf(ah[t] * xh[2 * jj], ah[t] * xh[2 * jj + 1]);
            acc = __builtin_amdgcn_mfma_f32_16x16x32_bf16(a.v, bfr[t], acc, 0, 0, 0);
        }
        U8 a8;
        #pragma unroll
        for (int jj = 0; jj < 4; ++jj)
            a8.u[jj] = (q2 == 0) ? pack2bf(xh[2 * jj], xh[2 * jj + 1]) : 0u;
        acc = __builtin_amdgcn_mfma_f32_16x16x32_bf16(a8.v, bfr[8], acc, 0, 0, 0);

        int dl = (int)((peC.y >> 20) & (CBIN - 1));
        #pragma unroll
        for (int r = 0; r < 4; ++r) {
            int s2 = tC_ch * 16 + quad * 4 + r;
            int dlr = __shfl(dl, quad * 4 + r);
            if (s2 < tC_len)
                atomicAdd(&tile[dlr * 16 + m], acc[r]);
        }

        tC_g = tB_g; tC_ch = tB_ch; tC_len = tB_len; peC = peB; vmC = vmB;
        xC0 = xB0; xC1 = xB1; aC0 = aB0; aC1 = aB1;
        tB_g = tA_g; tB_ch = tA_ch; tB_len = tA_len; peB = peA; vmB = vmA;
        ADV(tA);
    }
    __syncthreads();

    float* __restrict__ pt =
        partial + ((size_t)(ms * BPM + bin) * SUBS + sub) * (CBIN * 16);
    for (int i = tid; i < CBIN * 16; i += 512) pt[i] = tile[i];
}

// Parallel exact-f32 fallback: block b2 drains its own ovf list, 16 threads
// per edge, atomicAdd into the sub-0 partial copy. O(T) parallel, ~us-scale
// even at T ~ 1e5.
__global__ __launch_bounds__(256) void ovf_cleanup(
    const int* __restrict__ ei_a, const float* __restrict__ ea_a,
    const float* __restrict__ x_a,
    const float* __restrict__ w_msg_a, const float* __restrict__ b_msg_a,
    const int* __restrict__ ei_b, const float* __restrict__ ea_b,
    const float* __restrict__ x_b,
    const float* __restrict__ w_msg_b, const float* __restrict__ b_msg_b,
    float* __restrict__ partial,
    const unsigned int* __restrict__ ovf_n, const unsigned int* __restrict__ ovf)
{
    int b2 = blockIdx.x;
    unsigned int c2 = ovf_n[b2];
    if (c2 == 0) return;
    int ms = b2 >= ABM;
    const int* ei = ms ? ei_b : ei_a;
    const float* ea = ms ? ea_b : ea_a;
    const float* xs = ms ? x_b : x_a;
    const float* w_msg = ms ? w_msg_b : w_msg_a;
    const float* b_msg = ms ? b_msg_b : b_msg_a;
    int total = (int)c2 * 16;
    for (int idx = threadIdx.x; idx < total; idx += 256) {
        int o = idx & 15;
        int e = (int)ovf[(size_t)b2 * OVB + (idx >> 4)];
        int src = ei[e], dst = ei[EE + e];
        const float* ar = ea + (size_t)e * 16;
        const float* xj = xs + (size_t)src * 16;
        float acc = 0.f;
        #pragma unroll
        for (int i = 0; i < 16; ++i) {
            float we = b_msg[i * 16 + o];
            #pragma unroll
            for (int f = 0; f < 16; ++f)
                we += ar[f] * w_msg[f * 256 + i * 16 + o];
            acc += xj[i] * we;
        }
        size_t slot = ((size_t)(ms * BPM + (dst >> SHIFT)) * SUBS) * (CBIN * 16)
                      + (size_t)(dst & (CBIN - 1)) * 16 + o;
        atomicAdd(&partial[slot], acc);
    }
}

// out[n,d] = sigmoid( h @ w_lin + b_lin ),
// h = sigmoid( sum_subs partial + x@root + bias )
__global__ __launch_bounds__(256) void finalize(
    const float* __restrict__ xind, const float* __restrict__ partial,
    const float* __restrict__ root_a, const float* __restrict__ bias_a,
    const float* __restrict__ root_b, const float* __restrict__ bias_b,
    const float* __restrict__ w_lin, const float* __restrict__ b_lin,
    float* __restrict__ out)
{
    int tid = threadIdx.x;
    int n = blockIdx.x * 8 + (tid >> 5);
    if (n >= NN) return;
    int d = tid & 31;
    int lane = tid & 63;
    int gb32 = lane & ~31;

    float xv = xind[n * 16 + (d & 15)];

    int j = d & 15;
    int ms = (d < 16) ? 0 : 1;
    const float* root = ms ? root_b : root_a;
    const float* bias = ms ? bias_b : bias_a;

    int bin = n >> SHIFT, dl = n & (CBIN - 1);
    const float* pa = partial + ((size_t)(ms * BPM + bin) * SUBS) * (CBIN * 16)
                      + (size_t)dl * 16 + j;
    float acc = pa[0] + pa[CBIN * 16] + bias[j];
    #pragma unroll
    for (int i = 0; i < 16; ++i) {
        float xiv = __shfl(xv, gb32 + i);
        acc += xiv * root[i * 16 + j];
    }
    float h = 1.f / (1.f + __expf(-acc));

    float acc2 = b_lin[d];
    #pragma unroll
    for (int jj = 0; jj < 32; ++jj) {
        float hj = __shfl(h, gb32 + jj);
        acc2 += hj * w_lin[jj * 32 + d];
    }
    out[(size_t)n * 32 + d] = 1.f / (1.f + __expf(-acc2));
}

extern "C" void kernel_launch(void* const* d_in, const int* in_sizes, int n_in,
                              void* d_out, int out_size, void* d_ws, size_t ws_size,
                              hipStream_t stream) {
    (void)in_sizes; (void)n_in; (void)out_size; (void)ws_size;
    const float* x_indivi = (const float*)d_in[0];
    const float* x_src_a  = (const float*)d_in[1];
    const float* x_src_b  = (const float*)d_in[2];
    const int*   ei_a     = (const int*)d_in[3];
    const int*   ei_b     = (const int*)d_in[4];
    const float* ea_a     = (const float*)d_in[5];
    const float* ea_b     = (const float*)d_in[6];
    const float* w_msg_a  = (const float*)d_in[7];
    const float* b_msg_a  = (const float*)d_in[8];
    const float* root_a   = (const float*)d_in[9];
    const float* bias_a   = (const float*)d_in[10];
    const float* w_msg_b  = (const float*)d_in[11];
    const float* b_msg_b  = (const float*)d_in[12];
    const float* root_b   = (const float*)d_in[13];
    const float* bias_b   = (const float*)d_in[14];
    const float* w_lin    = (const float*)d_in[15];
    const float* b_lin    = (const float*)d_in[16];
    float* out = (float*)d_out;

    // Fixed budget: col 17.2MB + partial 12.85MB + ovf 3.2MB + misc ~0.1MB
    // = 33.4MB, below the 37MB proven by R9's working fixed layout.
    char* ws = (char*)d_ws;
    size_t off = 0;
    auto alloc = [&](size_t bytes) -> void* {
        void* p = ws + off;
        off += (bytes + 255) & ~(size_t)255;
        return p;
    };
    uint2* col = (uint2*)alloc((size_t)2 * BPM * ABM * CAPB * 8);        // 17.2 MB
    float* partial = (float*)alloc((size_t)2 * BPM * SUBS * CBIN * 16 * 4); // 12.85 MB
    unsigned int* ovf = (unsigned int*)alloc((size_t)2 * ABM * OVB * 4); // 3.2 MB
    unsigned short* wf_a = (unsigned short*)alloc(9 * 64 * 8 * 2);       // 9216 B
    unsigned short* wf_b = (unsigned short*)alloc(9 * 64 * 8 * 2);
    unsigned int* cntA   = (unsigned int*)alloc((size_t)2 * BPM * ABM * 4); // 77 KB
    unsigned int* ovf_n  = (unsigned int*)alloc((size_t)2 * ABM * 4);

    scatter_prep<<<2 * ABM + 2, 1024, 0, stream>>>(
        ei_a, ei_b, w_msg_a, b_msg_a, wf_a, w_msg_b, b_msg_b, wf_b,
        cntA, col, ovf_n, ovf);

    edge_mfma<<<BPM * 2 * SUBS, 512, 0, stream>>>(
        ea_a, x_src_a, wf_a, ea_b, x_src_b, wf_b, cntA, col, partial);

    ovf_cleanup<<<2 * ABM, 256, 0, stream>>>(
        ei_a, ea_a, x_src_a, w_msg_a, b_msg_a,
        ei_b, ea_b, x_src_b, w_msg_b, b_msg_b, partial, ovf_n, ovf);

    finalize<<<(NN + 7) / 8, 256, 0, stream>>>(
        x_indivi, partial, root_a, bias_a, root_b, bias_b, w_lin, b_lin, out);
}